// Round 4
// baseline (3152.005 us; speedup 1.0000x reference)
//
#include <hip/hip_runtime.h>
#include <stdint.h>

// QLinear HQQ 4-bit: out = x @ dequant(W_q).T + bias
// M=8192 tokens, N=4096 out features, K=4096 in features, group=64 along K.
//
// R6: 2 blocks/CU via 80 KB LDS (A: 3-slot ring 48 KB, B: 2-slot ring 32 KB).
// R5 post-mortem: within one barrier-locked block, the 96-read LDS drain
// (~1156 cy) and the MFMA cluster (~1242 cy) serialize (44% MfmaUtil, 21%
// occupancy, 1 block/CU at 96 KB). Cross-BLOCK overlap (m97/m114 mechanism)
// is the fix: two unsynchronized blocks per CU let one block's LDS phase
// run under the other's MFMA phase. Counted vmcnt preserved:
//   P0 issues B(T+1); P1 issues A(T+2) then vmcnt(2)
//   (queue oldest-first: A(T+1)x2, B(T+1)x2, A(T+2)x2 -> drains thru B(T+1)).
// Ring period lcm(3,2)=6 -> unroll-by-6 compile-time slots.
// __launch_bounds__(512,4): 4 waves/EU = 2 blocks/CU, VGPR cap 128 (have ~108).

typedef __attribute__((ext_vector_type(8))) _Float16 half8;
typedef __attribute__((ext_vector_type(4))) float f32x4;

#define M_DIM 8192
#define N_DIM 4096
#define K_DIM 4096

__device__ __forceinline__ void async16(const void* g, void* l) {
  // 16B/lane direct global->LDS. LDS dest is wave-uniform base + lane*16.
  __builtin_amdgcn_global_load_lds(
      (const __attribute__((address_space(1))) void*)g,
      (__attribute__((address_space(3))) void*)l,
      16, 0, 0);
}

// ---------------- stage 1 (fused): x fp32->f16  +  W_q dequant->f16 --------
__global__ __launch_bounds__(256) void prep(
    const float* __restrict__ x, const int* __restrict__ Wq,
    const float* __restrict__ scale, const float* __restrict__ zero,
    _Float16* __restrict__ xh, _Float16* __restrict__ wh) {
  const int b = blockIdx.x;
  if (b < 16384) {
    const size_t i = ((size_t)b * 256 + threadIdx.x) * 8;
    f32x4 a = *(const f32x4*)(x + i);
    f32x4 c = *(const f32x4*)(x + i + 4);
    half8 h;
    h[0] = (_Float16)a[0]; h[1] = (_Float16)a[1];
    h[2] = (_Float16)a[2]; h[3] = (_Float16)a[3];
    h[4] = (_Float16)c[0]; h[5] = (_Float16)c[1];
    h[6] = (_Float16)c[2]; h[7] = (_Float16)c[3];
    *(half8*)(xh + i) = h;
  } else {
    const int idx = (b - 16384) * 256 + threadIdx.x;  // 0..2097151, 8 elems
    const int o  = idx >> 9;                          // row 0..4095
    const int kb = (idx & 511) << 3;                  // col start, step 8
    const int g  = (o << 6) + (kb >> 6);              // group id
    const int j  = kb & 63;
    const bool hi = (o < 2048);
    const int* src = Wq + (size_t)(hi ? g : g - 131072) * 64 + j;
    const int4 v0 = *(const int4*)src;
    const int4 v1 = *(const int4*)(src + 4);
    const float s  = scale[g];
    const float nz = -zero[g] * s;                    // (nib - z)*s = nib*s + nz
    int raw[8] = {v0.x, v0.y, v0.z, v0.w, v1.x, v1.y, v1.z, v1.w};
    half8 h;
#pragma unroll
    for (int r = 0; r < 8; ++r) {
      const int nib = hi ? ((raw[r] >> 4) & 0xF) : (raw[r] & 0xF);
      h[r] = (_Float16)((float)nib * s + nz);
    }
    *(half8*)(wh + (size_t)o * K_DIM + kb) = h;
  }
}

// ---------------- stage 2: fine-phased f16 MFMA GEMM-BT, 2 blocks/CU -------
// Block tile 256x256, BK=32, 512 threads = 8 waves (2M x 4N), each wave a
// 128x64 sub-tile = 8x4 fragments of 16x16x32.
// LDS: A 3-slot ring (48 KB) + B 2-slot ring (32 KB) = 80 KB -> 2 blocks/CU.
__global__ __launch_bounds__(512, 4) void gemm_f16_fine(
    const _Float16* __restrict__ A, const _Float16* __restrict__ B,
    const float* __restrict__ bias, float* __restrict__ C) {
  __shared__ _Float16 As[3 * 8192];   // 48 KB: 3 slots of [256 rows][32 halfs]
  __shared__ _Float16 Bs[2 * 8192];   // 32 KB: 2 slots

  const int tid  = threadIdx.x;
  const int wave = tid >> 6;
  const int lane = tid & 63;
  const int quad = lane >> 4;
  const int l16  = lane & 15;
  const int wm   = wave >> 2;          // 0..1  (M half)
  const int wn   = wave & 3;           // 0..3  (N quarter)

  // XCD-aware swizzle: 512 blocks, 8 XCDs -> 64 contiguous per XCD.
  const int bid = blockIdx.x;
  const int swb = (bid & 7) * 64 + (bid >> 3);
  const int m0 = (swb >> 4) * 256;     // 32 row-blocks
  const int n0 = (swb & 15) * 256;     // 16 col-blocks

  // staging: thread t's 16B lands at LDS linear granule t (row t>>2, phys
  // granule t&3). Fetch LOGICAL granule (t&3)^((row>>1)&3) from global.
  const int srow = tid >> 2;                          // 0..127
  const int sg   = (((tid & 3) ^ ((tid >> 3) & 3)) << 3);
  const _Float16* gA0 = A + (size_t)(m0 + srow) * K_DIM + sg;      // rows 0..127
  const _Float16* gA1 = gA0 + (size_t)128 * K_DIM;                 // rows 128..255
  const _Float16* gB0 = B + (size_t)(n0 + srow) * K_DIM + sg;
  const _Float16* gB1 = gB0 + (size_t)128 * K_DIM;
  const int wst = wave * 512;          // wave-uniform stage offset (halfs)

  // fragment reads: un-swizzle with the same row-derived XOR
  const int fro  = ((quad ^ ((l16 >> 1) & 3)) << 3);  // granule offset (halfs)
  const int arow = wm * 128 + l16;                    // + i*16 (+64 for high)
  const int brow = wn * 64 + l16;                     // + j*16

  f32x4 acc[8][4] = {};

  const int NT = K_DIM / 32;           // 128

  // prologue: A(0)->slot0, B(0)->slot0, A(1)->slot1; wait all but A(1).
  async16(gA0,      As + wst);
  async16(gA1,      As + 4096 + wst);
  async16(gB0,      Bs + wst);
  async16(gB1,      Bs + 4096 + wst);
  async16(gA0 + 32, As + 8192 + wst);
  async16(gA1 + 32, As + 8192 + 4096 + wst);
  asm volatile("s_waitcnt vmcnt(2)" ::: "memory");
  __builtin_amdgcn_s_barrier();

// One K-tile = two fine phases. AR/BR/BW/AW are compile-time slot offsets
// (halfs). P0 issues B(T+1); P1 issues A(T+2) then vmcnt(2): outstanding
// queue oldest-first = A(T+1)x2, B(T+1)x2, A(T+2)x2 -> drains thru B(T+1).
#define KSTEP(AR, BR, BW, AW, T)                                             \
  {                                                                          \
    half8 aF[4], bF[4];                                                      \
    /* ---- P0: read aF_low + bF (first-use order), stage B(T+1) ---- */     \
    aF[0] = *(const half8*)(As + (AR) + (arow + 0 * 16) * 32 + fro);         \
    bF[0] = *(const half8*)(Bs + (BR) + (brow + 0 * 16) * 32 + fro);         \
    bF[1] = *(const half8*)(Bs + (BR) + (brow + 1 * 16) * 32 + fro);         \
    bF[2] = *(const half8*)(Bs + (BR) + (brow + 2 * 16) * 32 + fro);         \
    bF[3] = *(const half8*)(Bs + (BR) + (brow + 3 * 16) * 32 + fro);         \
    aF[1] = *(const half8*)(As + (AR) + (arow + 1 * 16) * 32 + fro);         \
    aF[2] = *(const half8*)(As + (AR) + (arow + 2 * 16) * 32 + fro);         \
    aF[3] = *(const half8*)(As + (AR) + (arow + 3 * 16) * 32 + fro);         \
    if ((T) + 1 < NT) {                                                      \
      const int k1 = ((T) + 1) * 32;                                         \
      async16(gB0 + k1, Bs + (BW) + wst);                                    \
      async16(gB1 + k1, Bs + (BW) + 4096 + wst);                             \
    }                                                                        \
    __builtin_amdgcn_s_barrier();                                            \
    __builtin_amdgcn_s_setprio(1);                                           \
    _Pragma("unroll") for (int i = 0; i < 4; ++i)                            \
      _Pragma("unroll") for (int j = 0; j < 4; ++j)                          \
        acc[i][j] = __builtin_amdgcn_mfma_f32_16x16x32_f16(                  \
            aF[i], bF[j], acc[i][j], 0, 0, 0);                               \
    __builtin_amdgcn_s_setprio(0);                                           \
    __builtin_amdgcn_s_barrier();                                            \
    /* ---- P1: read aF_high, stage A(T+2), counted vmcnt ---- */            \
    aF[0] = *(const half8*)(As + (AR) + (arow + 64 + 0 * 16) * 32 + fro);    \
    aF[1] = *(const half8*)(As + (AR) + (arow + 64 + 1 * 16) * 32 + fro);    \
    aF[2] = *(const half8*)(As + (AR) + (arow + 64 + 2 * 16) * 32 + fro);    \
    aF[3] = *(const half8*)(As + (AR) + (arow + 64 + 3 * 16) * 32 + fro);    \
    if ((T) + 2 < NT) {                                                      \
      const int k2 = ((T) + 2) * 32;                                         \
      async16(gA0 + k2, As + (AW) + wst);                                    \
      async16(gA1 + k2, As + (AW) + 4096 + wst);                             \
      asm volatile("s_waitcnt vmcnt(2)" ::: "memory");                       \
    } else {                                                                 \
      asm volatile("s_waitcnt vmcnt(0)" ::: "memory");                       \
    }                                                                        \
    __builtin_amdgcn_s_barrier();                                            \
    __builtin_amdgcn_s_setprio(1);                                           \
    _Pragma("unroll") for (int i = 0; i < 4; ++i)                            \
      _Pragma("unroll") for (int j = 0; j < 4; ++j)                          \
        acc[i + 4][j] = __builtin_amdgcn_mfma_f32_16x16x32_f16(              \
            aF[i], bF[j], acc[i + 4][j], 0, 0, 0);                           \
    __builtin_amdgcn_s_setprio(0);                                           \
    __builtin_amdgcn_s_barrier();                                            \
  }

  // main loop: ring period lcm(3,2)=6.  126 = 21*6; tail = 2.
  // (aR, bR, bW, aW) per T mod 6, slot offsets in halfs (slot = 8192).
  for (int T = 0; T < 126; T += 6) {
    KSTEP(0,     0,    8192, 16384, T)
    KSTEP(8192,  8192, 0,    0,     T + 1)
    KSTEP(16384, 0,    8192, 8192,  T + 2)
    KSTEP(0,     8192, 0,    16384, T + 3)
    KSTEP(8192,  0,    8192, 0,     T + 4)
    KSTEP(16384, 8192, 0,    8192,  T + 5)
  }
  KSTEP(0,    0,    8192, 16384, 126)
  KSTEP(8192, 8192, 0,    0,     127)
#undef KSTEP

  // epilogue: D row = quad*4 + reg, col = l16
#pragma unroll
  for (int j = 0; j < 4; ++j) {
    const int n = n0 + wn * 64 + j * 16 + l16;
    const float bv = bias[n];
#pragma unroll
    for (int i = 0; i < 8; ++i) {
      const int m = m0 + wm * 128 + i * 16 + quad * 4;
      float* p = C + (size_t)m * N_DIM + n;
      f32x4 v = acc[i][j];
      p[0 * N_DIM] = v[0] + bv;
      p[1 * N_DIM] = v[1] + bv;
      p[2 * N_DIM] = v[2] + bv;
      p[3 * N_DIM] = v[3] + bv;
    }
  }
}

// ---------------- fallback: fused fp32 GEMM, no workspace ----------------
__global__ __launch_bounds__(256) void gemm_fp32_fallback(
    const float* __restrict__ x, const int* __restrict__ Wq,
    const float* __restrict__ scale, const float* __restrict__ zero,
    const float* __restrict__ bias, float* __restrict__ C) {
  __shared__ float As[64][16];
  __shared__ float Bs[64][16];
  const int tid = threadIdx.x;
  const int m0 = blockIdx.y * 64;
  const int n0 = blockIdx.x * 64;
  const int tx = tid & 15;
  const int ty = tid >> 4;
  const int lr = tid >> 2;
  const int lc = (tid & 3) << 2;

  float acc[4][4] = {};

  for (int k0 = 0; k0 < K_DIM; k0 += 16) {
    __syncthreads();
    *(f32x4*)&As[lr][lc] = *(const f32x4*)(x + (size_t)(m0 + lr) * K_DIM + k0 + lc);
    {
      const int o = n0 + lr;
      const int k = k0 + lc;
      const int g = (o << 6) + (k >> 6);
      const bool hi = (o < 2048);
      const int* src = Wq + (size_t)(hi ? g : g - 131072) * 64 + (k & 63);
      const int4 v = *(const int4*)src;
      const float s = scale[g];
      const float nz = -zero[g] * s;
      f32x4 b;
      if (hi) {
        b[0] = (float)((v.x >> 4) & 0xF) * s + nz;
        b[1] = (float)((v.y >> 4) & 0xF) * s + nz;
        b[2] = (float)((v.z >> 4) & 0xF) * s + nz;
        b[3] = (float)((v.w >> 4) & 0xF) * s + nz;
      } else {
        b[0] = (float)(v.x & 0xF) * s + nz;
        b[1] = (float)(v.y & 0xF) * s + nz;
        b[2] = (float)(v.z & 0xF) * s + nz;
        b[3] = (float)(v.w & 0xF) * s + nz;
      }
      *(f32x4*)&Bs[lr][lc] = b;
    }
    __syncthreads();
#pragma unroll
    for (int kk = 0; kk < 16; ++kk) {
      float a[4], b[4];
#pragma unroll
      for (int r = 0; r < 4; ++r) a[r] = As[ty * 4 + r][kk];
#pragma unroll
      for (int c = 0; c < 4; ++c) b[c] = Bs[tx * 4 + c][kk];
#pragma unroll
      for (int r = 0; r < 4; ++r)
#pragma unroll
        for (int c = 0; c < 4; ++c) acc[r][c] += a[r] * b[c];
    }
  }
#pragma unroll
  for (int r = 0; r < 4; ++r)
#pragma unroll
    for (int c = 0; c < 4; ++c) {
      const int n = n0 + tx * 4 + c;
      C[(size_t)(m0 + ty * 4 + r) * N_DIM + n] = acc[r][c] + bias[n];
    }
}

extern "C" void kernel_launch(void* const* d_in, const int* in_sizes, int n_in,
                              void* d_out, int out_size, void* d_ws, size_t ws_size,
                              hipStream_t stream) {
  const float* x     = (const float*)d_in[0];
  const int*   Wq    = (const int*)d_in[1];
  const float* scale = (const float*)d_in[2];
  const float* zero  = (const float*)d_in[3];
  const float* bias  = (const float*)d_in[4];
  float* out = (float*)d_out;

  const size_t xh_bytes = (size_t)M_DIM * K_DIM * 2;  // 64 MB
  const size_t wh_bytes = (size_t)N_DIM * K_DIM * 2;  // 32 MB

  if (ws_size >= xh_bytes + wh_bytes) {
    _Float16* xh = (_Float16*)d_ws;
    _Float16* wh = (_Float16*)((char*)d_ws + xh_bytes);
    prep<<<16384 + 8192, 256, 0, stream>>>(x, Wq, scale, zero, xh, wh);
    gemm_f16_fine<<<(M_DIM / 256) * (N_DIM / 256), 512, 0, stream>>>(xh, wh, bias, out);
  } else {
    dim3 grid(N_DIM / 64, M_DIM / 64);    // (64, 128)
    gemm_fp32_fallback<<<grid, 256, 0, stream>>>(x, Wq, scale, zero, bias, out);
  }
}

// Round 5
// 519.926 us; speedup vs baseline: 6.0624x; 6.0624x over previous
//
#include <hip/hip_runtime.h>
#include <stdint.h>

// QLinear HQQ 4-bit: out = x @ dequant(W_q).T + bias
// M=8192 tokens, N=4096 out features, K=4096 in features, group=64 along K.
//
// R7: R6 post-mortem: __launch_bounds__(512,4) forced a <128-VGPR cap under
// a ~170-reg working set -> accumulator spill to scratch (VGPR 64, 8.7 GB
// writes/dispatch, 10x slower). Occupancy is REGISTER-bound at 2 waves/SIMD
// for the 256^2 tile; LDS size is not the constraint. Revert to (512,2).
// One change vs R5: staging depth. R5 issued B(T+1) in P0 of tile T and
// waited on it at end of P1 of tile T (~450 cy gap < ~900 cy HBM latency
// -> exposed stall every K-tile). Now BOTH A and B use 3-slot rings with
// stage distance 2: tile T stages A(T+2) in P0, B(T+2) in P1, vmcnt(4)
// leaves exactly those 4 loads in flight -> the wait targets tile T+1's
// loads issued a full K-tile (~2600 cy) earlier. Barriers/phases/swizzle
// byte-identical to R5 (R3-vs-R4 showed cutting barriers hurts here).

typedef __attribute__((ext_vector_type(8))) _Float16 half8;
typedef __attribute__((ext_vector_type(4))) float f32x4;

#define M_DIM 8192
#define N_DIM 4096
#define K_DIM 4096

__device__ __forceinline__ void async16(const void* g, void* l) {
  // 16B/lane direct global->LDS. LDS dest is wave-uniform base + lane*16.
  __builtin_amdgcn_global_load_lds(
      (const __attribute__((address_space(1))) void*)g,
      (__attribute__((address_space(3))) void*)l,
      16, 0, 0);
}

// ---------------- stage 1 (fused): x fp32->f16  +  W_q dequant->f16 --------
__global__ __launch_bounds__(256) void prep(
    const float* __restrict__ x, const int* __restrict__ Wq,
    const float* __restrict__ scale, const float* __restrict__ zero,
    _Float16* __restrict__ xh, _Float16* __restrict__ wh) {
  const int b = blockIdx.x;
  if (b < 16384) {
    const size_t i = ((size_t)b * 256 + threadIdx.x) * 8;
    f32x4 a = *(const f32x4*)(x + i);
    f32x4 c = *(const f32x4*)(x + i + 4);
    half8 h;
    h[0] = (_Float16)a[0]; h[1] = (_Float16)a[1];
    h[2] = (_Float16)a[2]; h[3] = (_Float16)a[3];
    h[4] = (_Float16)c[0]; h[5] = (_Float16)c[1];
    h[6] = (_Float16)c[2]; h[7] = (_Float16)c[3];
    *(half8*)(xh + i) = h;
  } else {
    const int idx = (b - 16384) * 256 + threadIdx.x;  // 0..2097151, 8 elems
    const int o  = idx >> 9;                          // row 0..4095
    const int kb = (idx & 511) << 3;                  // col start, step 8
    const int g  = (o << 6) + (kb >> 6);              // group id
    const int j  = kb & 63;
    const bool hi = (o < 2048);
    const int* src = Wq + (size_t)(hi ? g : g - 131072) * 64 + j;
    const int4 v0 = *(const int4*)src;
    const int4 v1 = *(const int4*)(src + 4);
    const float s  = scale[g];
    const float nz = -zero[g] * s;                    // (nib - z)*s = nib*s + nz
    int raw[8] = {v0.x, v0.y, v0.z, v0.w, v1.x, v1.y, v1.z, v1.w};
    half8 h;
#pragma unroll
    for (int r = 0; r < 8; ++r) {
      const int nib = hi ? ((raw[r] >> 4) & 0xF) : (raw[r] & 0xF);
      h[r] = (_Float16)((float)nib * s + nz);
    }
    *(half8*)(wh + (size_t)o * K_DIM + kb) = h;
  }
}

// ---------------- stage 2: fine-phased f16 MFMA GEMM-BT --------------------
// Block tile 256x256, BK=32, 512 threads = 8 waves (2M x 4N), each wave a
// 128x64 sub-tile = 8x4 fragments of 16x16x32.
// LDS: A 3-slot ring (48 KB) + B 3-slot ring (48 KB) = 96 KB, 1 block/CU
// (register-bound to 2 waves/SIMD regardless -- R6 evidence).
__global__ __launch_bounds__(512, 2) void gemm_f16_fine(
    const _Float16* __restrict__ A, const _Float16* __restrict__ B,
    const float* __restrict__ bias, float* __restrict__ C) {
  __shared__ _Float16 As[3 * 8192];   // 48 KB: 3 slots of [256 rows][32 halfs]
  __shared__ _Float16 Bs[3 * 8192];   // 48 KB

  const int tid  = threadIdx.x;
  const int wave = tid >> 6;
  const int lane = tid & 63;
  const int quad = lane >> 4;
  const int l16  = lane & 15;
  const int wm   = wave >> 2;          // 0..1  (M half)
  const int wn   = wave & 3;           // 0..3  (N quarter)

  // XCD-aware swizzle: 512 blocks, 8 XCDs -> 64 contiguous per XCD.
  const int bid = blockIdx.x;
  const int swb = (bid & 7) * 64 + (bid >> 3);
  const int m0 = (swb >> 4) * 256;     // 32 row-blocks
  const int n0 = (swb & 15) * 256;     // 16 col-blocks

  // staging: thread t's 16B lands at LDS linear granule t (row t>>2, phys
  // granule t&3). Fetch LOGICAL granule (t&3)^((row>>1)&3) from global.
  const int srow = tid >> 2;                          // 0..127
  const int sg   = (((tid & 3) ^ ((tid >> 3) & 3)) << 3);
  const _Float16* gA0 = A + (size_t)(m0 + srow) * K_DIM + sg;      // rows 0..127
  const _Float16* gA1 = gA0 + (size_t)128 * K_DIM;                 // rows 128..255
  const _Float16* gB0 = B + (size_t)(n0 + srow) * K_DIM + sg;
  const _Float16* gB1 = gB0 + (size_t)128 * K_DIM;
  const int wst = wave * 512;          // wave-uniform stage offset (halfs)

  // fragment reads: un-swizzle with the same row-derived XOR
  const int fro  = ((quad ^ ((l16 >> 1) & 3)) << 3);  // granule offset (halfs)
  const int arow = wm * 128 + l16;                    // + i*16 (+64 for high)
  const int brow = wn * 64 + l16;                     // + j*16

  f32x4 acc[8][4] = {};

  const int NT = K_DIM / 32;           // 128

  // prologue: tile0 -> slot0 (A,B), tile1 -> slot1 (A,B); wait tile0 only
  // (vmcnt(4) leaves tile1's 4 loads in flight).
  async16(gA0,      As + wst);
  async16(gA1,      As + 4096 + wst);
  async16(gB0,      Bs + wst);
  async16(gB1,      Bs + 4096 + wst);
  async16(gA0 + 32, As + 8192 + wst);
  async16(gA1 + 32, As + 8192 + 4096 + wst);
  async16(gB0 + 32, Bs + 8192 + wst);
  async16(gB1 + 32, Bs + 8192 + 4096 + wst);
  asm volatile("s_waitcnt vmcnt(4)" ::: "memory");
  __builtin_amdgcn_s_barrier();

// One K-tile = two fine phases. RD/WR are compile-time slot offsets (halfs).
// P0 stages A(T+2)->As+WR; P1 stages B(T+2)->Bs+WR then vmcnt(4): the 4
// outstanding loads are exactly tile T+2's -> tile T+1 (issued a full
// K-tile earlier, ~2600 cy > ~900 cy HBM latency) has landed.
// Slot safety: slot (T+2)%3 was last read at tile T-1; those reads
// completed before tile T-1's MFMA (compiler lgkmcnt) which precedes the
// barrier that precedes these stage issues.
#define KSTEP(RD, WR, T)                                                     \
  {                                                                          \
    half8 aF[4], bF[4];                                                      \
    /* ---- P0: read aF_low + bF (first-use order), stage A(T+2) ---- */     \
    aF[0] = *(const half8*)(As + (RD) + (arow + 0 * 16) * 32 + fro);         \
    bF[0] = *(const half8*)(Bs + (RD) + (brow + 0 * 16) * 32 + fro);         \
    bF[1] = *(const half8*)(Bs + (RD) + (brow + 1 * 16) * 32 + fro);         \
    bF[2] = *(const half8*)(Bs + (RD) + (brow + 2 * 16) * 32 + fro);         \
    bF[3] = *(const half8*)(Bs + (RD) + (brow + 3 * 16) * 32 + fro);         \
    aF[1] = *(const half8*)(As + (RD) + (arow + 1 * 16) * 32 + fro);         \
    aF[2] = *(const half8*)(As + (RD) + (arow + 2 * 16) * 32 + fro);         \
    aF[3] = *(const half8*)(As + (RD) + (arow + 3 * 16) * 32 + fro);         \
    if ((T) + 2 < NT) {                                                      \
      const int k2 = ((T) + 2) * 32;                                         \
      async16(gA0 + k2, As + (WR) + wst);                                    \
      async16(gA1 + k2, As + (WR) + 4096 + wst);                             \
    }                                                                        \
    __builtin_amdgcn_s_barrier();                                            \
    __builtin_amdgcn_s_setprio(1);                                           \
    _Pragma("unroll") for (int i = 0; i < 4; ++i)                            \
      _Pragma("unroll") for (int j = 0; j < 4; ++j)                          \
        acc[i][j] = __builtin_amdgcn_mfma_f32_16x16x32_f16(                  \
            aF[i], bF[j], acc[i][j], 0, 0, 0);                               \
    __builtin_amdgcn_s_setprio(0);                                           \
    __builtin_amdgcn_s_barrier();                                            \
    /* ---- P1: read aF_high, stage B(T+2), counted vmcnt ---- */            \
    aF[0] = *(const half8*)(As + (RD) + (arow + 64 + 0 * 16) * 32 + fro);    \
    aF[1] = *(const half8*)(As + (RD) + (arow + 64 + 1 * 16) * 32 + fro);    \
    aF[2] = *(const half8*)(As + (RD) + (arow + 64 + 2 * 16) * 32 + fro);    \
    aF[3] = *(const half8*)(As + (RD) + (arow + 64 + 3 * 16) * 32 + fro);    \
    if ((T) + 2 < NT) {                                                      \
      const int k2 = ((T) + 2) * 32;                                         \
      async16(gB0 + k2, Bs + (WR) + wst);                                    \
      async16(gB1 + k2, Bs + (WR) + 4096 + wst);                             \
      asm volatile("s_waitcnt vmcnt(4)" ::: "memory");                       \
    } else {                                                                 \
      asm volatile("s_waitcnt vmcnt(0)" ::: "memory");                       \
    }                                                                        \
    __builtin_amdgcn_s_barrier();                                            \
    __builtin_amdgcn_s_setprio(1);                                           \
    _Pragma("unroll") for (int i = 0; i < 4; ++i)                            \
      _Pragma("unroll") for (int j = 0; j < 4; ++j)                          \
        acc[i + 4][j] = __builtin_amdgcn_mfma_f32_16x16x32_f16(              \
            aF[i], bF[j], acc[i + 4][j], 0, 0, 0);                           \
    __builtin_amdgcn_s_setprio(0);                                           \
    __builtin_amdgcn_s_barrier();                                            \
  }

  // main loop: ring period 3 for both A and B; slots compile-time.
  // T%3 -> (RD, WR): 0:(0,16384) 1:(8192,0) 2:(16384,8192).
  for (int T = 0; T < 126; T += 3) {
    KSTEP(0,     16384, T)
    KSTEP(8192,  0,     T + 1)
    KSTEP(16384, 8192,  T + 2)
  }
  KSTEP(0,    16384, 126)
  KSTEP(8192, 0,     127)
#undef KSTEP

  // epilogue: D row = quad*4 + reg, col = l16
#pragma unroll
  for (int j = 0; j < 4; ++j) {
    const int n = n0 + wn * 64 + j * 16 + l16;
    const float bv = bias[n];
#pragma unroll
    for (int i = 0; i < 8; ++i) {
      const int m = m0 + wm * 128 + i * 16 + quad * 4;
      float* p = C + (size_t)m * N_DIM + n;
      f32x4 v = acc[i][j];
      p[0 * N_DIM] = v[0] + bv;
      p[1 * N_DIM] = v[1] + bv;
      p[2 * N_DIM] = v[2] + bv;
      p[3 * N_DIM] = v[3] + bv;
    }
  }
}

// ---------------- fallback: fused fp32 GEMM, no workspace ----------------
__global__ __launch_bounds__(256) void gemm_fp32_fallback(
    const float* __restrict__ x, const int* __restrict__ Wq,
    const float* __restrict__ scale, const float* __restrict__ zero,
    const float* __restrict__ bias, float* __restrict__ C) {
  __shared__ float As[64][16];
  __shared__ float Bs[64][16];
  const int tid = threadIdx.x;
  const int m0 = blockIdx.y * 64;
  const int n0 = blockIdx.x * 64;
  const int tx = tid & 15;
  const int ty = tid >> 4;
  const int lr = tid >> 2;
  const int lc = (tid & 3) << 2;

  float acc[4][4] = {};

  for (int k0 = 0; k0 < K_DIM; k0 += 16) {
    __syncthreads();
    *(f32x4*)&As[lr][lc] = *(const f32x4*)(x + (size_t)(m0 + lr) * K_DIM + k0 + lc);
    {
      const int o = n0 + lr;
      const int k = k0 + lc;
      const int g = (o << 6) + (k >> 6);
      const bool hi = (o < 2048);
      const int* src = Wq + (size_t)(hi ? g : g - 131072) * 64 + (k & 63);
      const int4 v = *(const int4*)src;
      const float s = scale[g];
      const float nz = -zero[g] * s;
      f32x4 b;
      if (hi) {
        b[0] = (float)((v.x >> 4) & 0xF) * s + nz;
        b[1] = (float)((v.y >> 4) & 0xF) * s + nz;
        b[2] = (float)((v.z >> 4) & 0xF) * s + nz;
        b[3] = (float)((v.w >> 4) & 0xF) * s + nz;
      } else {
        b[0] = (float)(v.x & 0xF) * s + nz;
        b[1] = (float)(v.y & 0xF) * s + nz;
        b[2] = (float)(v.z & 0xF) * s + nz;
        b[3] = (float)(v.w & 0xF) * s + nz;
      }
      *(f32x4*)&Bs[lr][lc] = b;
    }
    __syncthreads();
#pragma unroll
    for (int kk = 0; kk < 16; ++kk) {
      float a[4], b[4];
#pragma unroll
      for (int r = 0; r < 4; ++r) a[r] = As[ty * 4 + r][kk];
#pragma unroll
      for (int c = 0; c < 4; ++c) b[c] = Bs[tx * 4 + c][kk];
#pragma unroll
      for (int r = 0; r < 4; ++r)
#pragma unroll
        for (int c = 0; c < 4; ++c) acc[r][c] += a[r] * b[c];
    }
  }
#pragma unroll
  for (int r = 0; r < 4; ++r)
#pragma unroll
    for (int c = 0; c < 4; ++c) {
      const int n = n0 + tx * 4 + c;
      C[(size_t)(m0 + ty * 4 + r) * N_DIM + n] = acc[r][c] + bias[n];
    }
}

extern "C" void kernel_launch(void* const* d_in, const int* in_sizes, int n_in,
                              void* d_out, int out_size, void* d_ws, size_t ws_size,
                              hipStream_t stream) {
  const float* x     = (const float*)d_in[0];
  const int*   Wq    = (const int*)d_in[1];
  const float* scale = (const float*)d_in[2];
  const float* zero  = (const float*)d_in[3];
  const float* bias  = (const float*)d_in[4];
  float* out = (float*)d_out;

  const size_t xh_bytes = (size_t)M_DIM * K_DIM * 2;  // 64 MB
  const size_t wh_bytes = (size_t)N_DIM * K_DIM * 2;  // 32 MB

  if (ws_size >= xh_bytes + wh_bytes) {
    _Float16* xh = (_Float16*)d_ws;
    _Float16* wh = (_Float16*)((char*)d_ws + xh_bytes);
    prep<<<16384 + 8192, 256, 0, stream>>>(x, Wq, scale, zero, xh, wh);
    gemm_f16_fine<<<(M_DIM / 256) * (N_DIM / 256), 512, 0, stream>>>(xh, wh, bias, out);
  } else {
    dim3 grid(N_DIM / 64, M_DIM / 64);    // (64, 128)
    gemm_fp32_fallback<<<grid, 256, 0, stream>>>(x, Wq, scale, zero, bias, out);
  }
}

// Round 6
// 512.165 us; speedup vs baseline: 6.1543x; 1.0152x over previous
//
#include <hip/hip_runtime.h>
#include <stdint.h>

// QLinear HQQ 4-bit: out = x @ dequant(W_q).T + bias
// M=8192 tokens, N=4096 out features, K=4096 in features, group=64 along K.
//
// R8: register-level fragment pipelining. R5/R7 showed the 44%-util plateau
// is strict serialization: LDS fragment drain (768cy) + LDS stage-writes
// (256cy) + MFMA (1242cy) per K-tile, alternating across barrier intervals.
// Fix: issue fragment ds_reads one phase EARLY so they drain UNDER the MFMA
// clusters (DS completes in-order; compiler lgkmcnt waits only through the
// operands actually needed, leaving later reads in flight):
//   tile T: read bF (exposed) + aFB(=aF-high, drains under MFMA-P0);
//           MFMA-P0(aFA x bF); read NEXT tile's aF-low into aFA (drains
//           under MFMA-P1); MFMA-P1(aFB x bF); vmcnt; barrier.  ONE barrier
//           per tile -- all cross-wave orderings funnel through it.
// Reading tile T+1 during tile T requires T+1 landed by end of T-1:
// 4-slot ring, stage distance 3, vmcnt(4) (outstanding = T+2's 4 loads).
// Slot safety: stage at T writes slot (T+3)&3; readers of that slot were
// tile T-1 (incl. its early-reads during T-2), all before the end-of-T-1
// barrier. Early-read slot (T+1)&3 != stage slot (T+3)&3 (differ by 2 mod 4).

typedef __attribute__((ext_vector_type(8))) _Float16 half8;
typedef __attribute__((ext_vector_type(4))) float f32x4;

#define M_DIM 8192
#define N_DIM 4096
#define K_DIM 4096

__device__ __forceinline__ void async16(const void* g, void* l) {
  // 16B/lane direct global->LDS. LDS dest is wave-uniform base + lane*16.
  __builtin_amdgcn_global_load_lds(
      (const __attribute__((address_space(1))) void*)g,
      (__attribute__((address_space(3))) void*)l,
      16, 0, 0);
}

// ---------------- stage 1 (fused): x fp32->f16  +  W_q dequant->f16 --------
__global__ __launch_bounds__(256) void prep(
    const float* __restrict__ x, const int* __restrict__ Wq,
    const float* __restrict__ scale, const float* __restrict__ zero,
    _Float16* __restrict__ xh, _Float16* __restrict__ wh) {
  const int b = blockIdx.x;
  if (b < 16384) {
    const size_t i = ((size_t)b * 256 + threadIdx.x) * 8;
    f32x4 a = *(const f32x4*)(x + i);
    f32x4 c = *(const f32x4*)(x + i + 4);
    half8 h;
    h[0] = (_Float16)a[0]; h[1] = (_Float16)a[1];
    h[2] = (_Float16)a[2]; h[3] = (_Float16)a[3];
    h[4] = (_Float16)c[0]; h[5] = (_Float16)c[1];
    h[6] = (_Float16)c[2]; h[7] = (_Float16)c[3];
    *(half8*)(xh + i) = h;
  } else {
    const int idx = (b - 16384) * 256 + threadIdx.x;  // 0..2097151, 8 elems
    const int o  = idx >> 9;                          // row 0..4095
    const int kb = (idx & 511) << 3;                  // col start, step 8
    const int g  = (o << 6) + (kb >> 6);              // group id
    const int j  = kb & 63;
    const bool hi = (o < 2048);
    const int* src = Wq + (size_t)(hi ? g : g - 131072) * 64 + j;
    const int4 v0 = *(const int4*)src;
    const int4 v1 = *(const int4*)(src + 4);
    const float s  = scale[g];
    const float nz = -zero[g] * s;                    // (nib - z)*s = nib*s + nz
    int raw[8] = {v0.x, v0.y, v0.z, v0.w, v1.x, v1.y, v1.z, v1.w};
    half8 h;
#pragma unroll
    for (int r = 0; r < 8; ++r) {
      const int nib = hi ? ((raw[r] >> 4) & 0xF) : (raw[r] & 0xF);
      h[r] = (_Float16)((float)nib * s + nz);
    }
    *(half8*)(wh + (size_t)o * K_DIM + kb) = h;
  }
}

// ---------------- stage 2: register-pipelined f16 MFMA GEMM-BT -------------
// Block tile 256x256, BK=32, 512 threads = 8 waves (2M x 4N), each wave a
// 128x64 sub-tile = 8x4 fragments of 16x16x32.
// LDS: A 4-slot ring (64 KB) + B 4-slot ring (64 KB) = 128 KB, 1 block/CU.
__global__ __launch_bounds__(512, 2) void gemm_f16_pipe(
    const _Float16* __restrict__ A, const _Float16* __restrict__ B,
    const float* __restrict__ bias, float* __restrict__ C) {
  __shared__ _Float16 As[4 * 8192];   // 64 KB: 4 slots of [256 rows][32 halfs]
  __shared__ _Float16 Bs[4 * 8192];   // 64 KB

  const int tid  = threadIdx.x;
  const int wave = tid >> 6;
  const int lane = tid & 63;
  const int quad = lane >> 4;
  const int l16  = lane & 15;
  const int wm   = wave >> 2;          // 0..1  (M half)
  const int wn   = wave & 3;           // 0..3  (N quarter)

  // XCD-aware swizzle: 512 blocks, 8 XCDs -> 64 contiguous per XCD.
  const int bid = blockIdx.x;
  const int swb = (bid & 7) * 64 + (bid >> 3);
  const int m0 = (swb >> 4) * 256;     // 32 row-blocks
  const int n0 = (swb & 15) * 256;     // 16 col-blocks

  // staging: thread t's 16B lands at LDS linear granule t (row t>>2, phys
  // granule t&3). Fetch LOGICAL granule (t&3)^((row>>1)&3) from global.
  const int srow = tid >> 2;                          // 0..127
  const int sg   = (((tid & 3) ^ ((tid >> 3) & 3)) << 3);
  const _Float16* gA0 = A + (size_t)(m0 + srow) * K_DIM + sg;      // rows 0..127
  const _Float16* gA1 = gA0 + (size_t)128 * K_DIM;                 // rows 128..255
  const _Float16* gB0 = B + (size_t)(n0 + srow) * K_DIM + sg;
  const _Float16* gB1 = gB0 + (size_t)128 * K_DIM;
  const int wst = wave * 512;          // wave-uniform stage offset (halfs)

  // fragment reads: un-swizzle with the same row-derived XOR
  const int fro  = ((quad ^ ((l16 >> 1) & 3)) << 3);  // granule offset (halfs)
  const int arow = wm * 128 + l16;                    // + i*16 (+64 for high)
  const int brow = wn * 64 + l16;                     // + j*16

  f32x4 acc[8][4] = {};
  half8 aFA[4], aFB[4], bF[4];

  // prologue: stage tiles 0,1,2 -> slots 0,1,2; vmcnt(4) -> tiles 0,1 landed
  // (tile 2's 4 loads stay in flight). Then preload tile 0's aF-low.
  async16(gA0,      As + wst);
  async16(gA1,      As + 4096 + wst);
  async16(gB0,      Bs + wst);
  async16(gB1,      Bs + 4096 + wst);
  async16(gA0 + 32, As + 8192 + wst);
  async16(gA1 + 32, As + 8192 + 4096 + wst);
  async16(gB0 + 32, Bs + 8192 + wst);
  async16(gB1 + 32, Bs + 8192 + 4096 + wst);
  async16(gA0 + 64, As + 16384 + wst);
  async16(gA1 + 64, As + 16384 + 4096 + wst);
  async16(gB0 + 64, Bs + 16384 + wst);
  async16(gB1 + 64, Bs + 16384 + 4096 + wst);
  asm volatile("s_waitcnt vmcnt(4)" ::: "memory");
  __builtin_amdgcn_s_barrier();
  aFA[0] = *(const half8*)(As + (arow + 0 * 16) * 32 + fro);
  aFA[1] = *(const half8*)(As + (arow + 1 * 16) * 32 + fro);
  aFA[2] = *(const half8*)(As + (arow + 2 * 16) * 32 + fro);
  aFA[3] = *(const half8*)(As + (arow + 3 * 16) * 32 + fro);

// One K-tile. SR/SN/SW compile-time slot offsets (halfs); KK2 = (T+3)*32.
// DS in-order completion: the lgkmcnt before MFMA-P0 drains through bF
// (leaving aFB in flight -> hides under P0); before MFMA-P1 drains through
// aFB (leaving next-aFA in flight -> hides under P1).
#define KSTEP(SR, SN, SW, KK2, STAGE_OK, NEXT_OK, VMW)                       \
  {                                                                          \
    bF[0] = *(const half8*)(Bs + (SR) + (brow + 0 * 16) * 32 + fro);         \
    bF[1] = *(const half8*)(Bs + (SR) + (brow + 1 * 16) * 32 + fro);         \
    bF[2] = *(const half8*)(Bs + (SR) + (brow + 2 * 16) * 32 + fro);         \
    bF[3] = *(const half8*)(Bs + (SR) + (brow + 3 * 16) * 32 + fro);         \
    aFB[0] = *(const half8*)(As + (SR) + (arow + 64 + 0 * 16) * 32 + fro);   \
    aFB[1] = *(const half8*)(As + (SR) + (arow + 64 + 1 * 16) * 32 + fro);   \
    aFB[2] = *(const half8*)(As + (SR) + (arow + 64 + 2 * 16) * 32 + fro);   \
    aFB[3] = *(const half8*)(As + (SR) + (arow + 64 + 3 * 16) * 32 + fro);   \
    if (STAGE_OK) {                                                          \
      async16(gA0 + (KK2), As + (SW) + wst);                                 \
      async16(gA1 + (KK2), As + (SW) + 4096 + wst);                          \
    }                                                                        \
    __builtin_amdgcn_s_setprio(1);                                           \
    _Pragma("unroll") for (int i = 0; i < 4; ++i)                            \
      _Pragma("unroll") for (int j = 0; j < 4; ++j)                          \
        acc[i][j] = __builtin_amdgcn_mfma_f32_16x16x32_f16(                  \
            aFA[i], bF[j], acc[i][j], 0, 0, 0);                              \
    __builtin_amdgcn_s_setprio(0);                                           \
    if (NEXT_OK) {                                                           \
      aFA[0] = *(const half8*)(As + (SN) + (arow + 0 * 16) * 32 + fro);      \
      aFA[1] = *(const half8*)(As + (SN) + (arow + 1 * 16) * 32 + fro);      \
      aFA[2] = *(const half8*)(As + (SN) + (arow + 2 * 16) * 32 + fro);      \
      aFA[3] = *(const half8*)(As + (SN) + (arow + 3 * 16) * 32 + fro);      \
    }                                                                        \
    if (STAGE_OK) {                                                          \
      async16(gB0 + (KK2), Bs + (SW) + wst);                                 \
      async16(gB1 + (KK2), Bs + (SW) + 4096 + wst);                          \
    }                                                                        \
    __builtin_amdgcn_s_setprio(1);                                           \
    _Pragma("unroll") for (int i = 0; i < 4; ++i)                            \
      _Pragma("unroll") for (int j = 0; j < 4; ++j)                          \
        acc[i + 4][j] = __builtin_amdgcn_mfma_f32_16x16x32_f16(              \
            aFB[i], bF[j], acc[i + 4][j], 0, 0, 0);                          \
    __builtin_amdgcn_s_setprio(0);                                           \
    asm volatile("s_waitcnt vmcnt(" #VMW ")" ::: "memory");                  \
    __builtin_amdgcn_s_barrier();                                            \
  }

  // main loop: tiles 0..123, ring period 4; stages tiles 3..126.
  for (int T = 0; T < 124; T += 4) {
    KSTEP(0,     8192,  24576, (T + 3) * 32, 1, 1, 4)
    KSTEP(8192,  16384, 0,     (T + 4) * 32, 1, 1, 4)
    KSTEP(16384, 24576, 8192,  (T + 5) * 32, 1, 1, 4)
    KSTEP(24576, 0,     16384, (T + 6) * 32, 1, 1, 4)
  }
  // tail: tiles 124 (stages 127), 125, 126, 127.
  KSTEP(0,     8192,  24576, 127 * 32, 1, 1, 4)
  KSTEP(8192,  16384, 0,     0,        0, 1, 0)
  KSTEP(16384, 24576, 8192,  0,        0, 1, 0)
  KSTEP(24576, 0,     16384, 0,        0, 0, 0)
#undef KSTEP

  // epilogue: D row = quad*4 + reg, col = l16
#pragma unroll
  for (int j = 0; j < 4; ++j) {
    const int n = n0 + wn * 64 + j * 16 + l16;
    const float bv = bias[n];
#pragma unroll
    for (int i = 0; i < 8; ++i) {
      const int m = m0 + wm * 128 + i * 16 + quad * 4;
      float* p = C + (size_t)m * N_DIM + n;
      f32x4 v = acc[i][j];
      p[0 * N_DIM] = v[0] + bv;
      p[1 * N_DIM] = v[1] + bv;
      p[2 * N_DIM] = v[2] + bv;
      p[3 * N_DIM] = v[3] + bv;
    }
  }
}

// ---------------- fallback: fused fp32 GEMM, no workspace ----------------
__global__ __launch_bounds__(256) void gemm_fp32_fallback(
    const float* __restrict__ x, const int* __restrict__ Wq,
    const float* __restrict__ scale, const float* __restrict__ zero,
    const float* __restrict__ bias, float* __restrict__ C) {
  __shared__ float As[64][16];
  __shared__ float Bs[64][16];
  const int tid = threadIdx.x;
  const int m0 = blockIdx.y * 64;
  const int n0 = blockIdx.x * 64;
  const int tx = tid & 15;
  const int ty = tid >> 4;
  const int lr = tid >> 2;
  const int lc = (tid & 3) << 2;

  float acc[4][4] = {};

  for (int k0 = 0; k0 < K_DIM; k0 += 16) {
    __syncthreads();
    *(f32x4*)&As[lr][lc] = *(const f32x4*)(x + (size_t)(m0 + lr) * K_DIM + k0 + lc);
    {
      const int o = n0 + lr;
      const int k = k0 + lc;
      const int g = (o << 6) + (k >> 6);
      const bool hi = (o < 2048);
      const int* src = Wq + (size_t)(hi ? g : g - 131072) * 64 + (k & 63);
      const int4 v = *(const int4*)src;
      const float s = scale[g];
      const float nz = -zero[g] * s;
      f32x4 b;
      if (hi) {
        b[0] = (float)((v.x >> 4) & 0xF) * s + nz;
        b[1] = (float)((v.y >> 4) & 0xF) * s + nz;
        b[2] = (float)((v.z >> 4) & 0xF) * s + nz;
        b[3] = (float)((v.w >> 4) & 0xF) * s + nz;
      } else {
        b[0] = (float)(v.x & 0xF) * s + nz;
        b[1] = (float)(v.y & 0xF) * s + nz;
        b[2] = (float)(v.z & 0xF) * s + nz;
        b[3] = (float)(v.w & 0xF) * s + nz;
      }
      *(f32x4*)&Bs[lr][lc] = b;
    }
    __syncthreads();
#pragma unroll
    for (int kk = 0; kk < 16; ++kk) {
      float a[4], b[4];
#pragma unroll
      for (int r = 0; r < 4; ++r) a[r] = As[ty * 4 + r][kk];
#pragma unroll
      for (int c = 0; c < 4; ++c) b[c] = Bs[tx * 4 + c][kk];
#pragma unroll
      for (int r = 0; r < 4; ++r)
#pragma unroll
        for (int c = 0; c < 4; ++c) acc[r][c] += a[r] * b[c];
    }
  }
#pragma unroll
  for (int r = 0; r < 4; ++r)
#pragma unroll
    for (int c = 0; c < 4; ++c) {
      const int n = n0 + tx * 4 + c;
      C[(size_t)(m0 + ty * 4 + r) * N_DIM + n] = acc[r][c] + bias[n];
    }
}

extern "C" void kernel_launch(void* const* d_in, const int* in_sizes, int n_in,
                              void* d_out, int out_size, void* d_ws, size_t ws_size,
                              hipStream_t stream) {
  const float* x     = (const float*)d_in[0];
  const int*   Wq    = (const int*)d_in[1];
  const float* scale = (const float*)d_in[2];
  const float* zero  = (const float*)d_in[3];
  const float* bias  = (const float*)d_in[4];
  float* out = (float*)d_out;

  const size_t xh_bytes = (size_t)M_DIM * K_DIM * 2;  // 64 MB
  const size_t wh_bytes = (size_t)N_DIM * K_DIM * 2;  // 32 MB

  if (ws_size >= xh_bytes + wh_bytes) {
    _Float16* xh = (_Float16*)d_ws;
    _Float16* wh = (_Float16*)((char*)d_ws + xh_bytes);
    prep<<<16384 + 8192, 256, 0, stream>>>(x, Wq, scale, zero, xh, wh);
    gemm_f16_pipe<<<(M_DIM / 256) * (N_DIM / 256), 512, 0, stream>>>(xh, wh, bias, out);
  } else {
    dim3 grid(N_DIM / 64, M_DIM / 64);    // (64, 128)
    gemm_fp32_fallback<<<grid, 256, 0, stream>>>(x, Wq, scale, zero, bias, out);
  }
}